// Round 1
// baseline (3153.446 us; speedup 1.0000x reference)
//
#include <hip/hip_runtime.h>
#include <math.h>

#define NB 8
#define NN 4096
#define DD 256
#define CC 1024
#define NQ 8
#define ROWS (NB*NN)        // 32768

#define MT 64               // rows per block (argmin kernel)
#define NT 128              // codebook cols per tile
#define KC 64               // k chunk staged per iteration
#define AW 260              // padded A width (2-way bank alias = free, 16B aligned)

// ---------------------------------------------------------------------------
// Fused distance + argmin over the full codebook for 64 rows per block.
// score(r,c) = ||e_c||^2 - 2 * dot(res_r, e_c)   (||res||^2 constant over c)
// ---------------------------------------------------------------------------
__global__ __launch_bounds__(256, 1) void rvq_argmin(
    const float* __restrict__ res,
    const float* __restrict__ cbT,   // [DD][CC] this level, k-major
    const float* __restrict__ cn2,   // [CC] this level
    float* __restrict__ idx_out,     // indices-as-float region of d_out
    int level)
{
  __shared__ float Ash[MT][AW];      // 66,560 B
  __shared__ float Bsh[KC][NT];      // 32,768 B

  const int tid = threadIdx.x;
  const int tx = tid & 15;
  const int ty = tid >> 4;
  const size_t row0 = (size_t)blockIdx.x * MT;

  // ---- stage A (64 x 256) row-major, padded ----
  {
    const float* src = res + row0 * DD;
    #pragma unroll
    for (int it = 0; it < 16; ++it) {
      int lin = (it << 8) + tid;          // float4 index 0..4095
      int r = lin >> 6;
      int k4 = (lin & 63) << 2;
      float4 v = *reinterpret_cast<const float4*>(src + r * DD + k4);
      *reinterpret_cast<float4*>(&Ash[r][k4]) = v;
    }
  }

  float bestv[4];
  int   bestc[4];
  #pragma unroll
  for (int i = 0; i < 4; ++i) { bestv[i] = __builtin_inff(); bestc[i] = 0; }

  float4 breg[8];  // register prefetch of next B chunk (128 cols x 64 k)

  auto load_chunk = [&](int m) {     // m = ct*4 + kk
    const int ct = m >> 2, kk = m & 3;
    const float* base = cbT + (size_t)(kk * KC) * CC + ct * NT;
    #pragma unroll
    for (int p = 0; p < 8; ++p) {
      int lin = (p << 8) + tid;         // float4 index 0..2047
      int k  = lin >> 5;                // 32 float4 per k-row
      int c4 = (lin & 31) << 2;
      breg[p] = *reinterpret_cast<const float4*>(base + (size_t)k * CC + c4);
    }
  };

  load_chunk(0);

  const int r0 = ty << 2;
  const int c0 = tx << 3;

  for (int ct = 0; ct < 8; ++ct) {
    float acc[4][8];
    #pragma unroll
    for (int i = 0; i < 4; ++i)
      #pragma unroll
      for (int j = 0; j < 8; ++j) acc[i][j] = 0.f;

    for (int kk = 0; kk < 4; ++kk) {
      const int m = (ct << 2) + kk;
      __syncthreads();                 // everyone done computing previous chunk
      #pragma unroll
      for (int p = 0; p < 8; ++p) {
        int lin = (p << 8) + tid;
        *reinterpret_cast<float4*>(&Bsh[0][0] + ((size_t)lin << 2)) = breg[p];
      }
      if (m + 1 < 32) load_chunk(m + 1);   // async global loads hide under compute
      __syncthreads();

      #pragma unroll 8
      for (int k = 0; k < KC; ++k) {
        float a[4];
        a[0] = Ash[r0 + 0][k];
        a[1] = Ash[r0 + 1][k];
        a[2] = Ash[r0 + 2][k];
        a[3] = Ash[r0 + 3][k];
        // note: Ash column index is kk*64 + k of the full K; but we staged the
        // full 256-wide rows, so index is (kk<<6)+k
        const int kcol = (kk << 6) + k;
        a[0] = Ash[r0 + 0][kcol];
        a[1] = Ash[r0 + 1][kcol];
        a[2] = Ash[r0 + 2][kcol];
        a[3] = Ash[r0 + 3][kcol];
        const float4 b0 = *reinterpret_cast<const float4*>(&Bsh[k][c0]);
        const float4 b1 = *reinterpret_cast<const float4*>(&Bsh[k][c0 + 4]);
        float b[8] = {b0.x, b0.y, b0.z, b0.w, b1.x, b1.y, b1.z, b1.w};
        #pragma unroll
        for (int i = 0; i < 4; ++i)
          #pragma unroll
          for (int j = 0; j < 8; ++j)
            acc[i][j] = fmaf(a[i], b[j], acc[i][j]);
      }
    }

    // ---- epilogue: argmin over this 128-col tile, fold into running best ----
    #pragma unroll
    for (int i = 0; i < 4; ++i) {
      float bv = __builtin_inff();
      int   bc = 0;
      #pragma unroll
      for (int j = 0; j < 8; ++j) {
        const int c = (ct << 7) + c0 + j;
        const float s = fmaf(-2.f, acc[i][j], cn2[c]);
        if (s < bv) { bv = s; bc = c; }      // ascending c: strict < keeps first
      }
      #pragma unroll
      for (int mm = 1; mm < 16; mm <<= 1) {
        const float ov = __shfl_xor(bv, mm);
        const int   oc = __shfl_xor(bc, mm);
        if (ov < bv || (ov == bv && oc < bc)) { bv = ov; bc = oc; }
      }
      if (bv < bestv[i]) { bestv[i] = bv; bestc[i] = bc; }  // tiles ascending
    }
  }

  if (tx == 0) {
    #pragma unroll
    for (int i = 0; i < 4; ++i)
      idx_out[(row0 + r0 + i) * NQ + level] = (float)bestc[i];
  }
}

// ---------------------------------------------------------------------------
// residual -= e[idx]; partial loss sums per block (4 rows/block)
// ---------------------------------------------------------------------------
__global__ __launch_bounds__(256) void rvq_update(
    float* __restrict__ res,
    const float* __restrict__ cb,     // this level's codebook [CC][DD]
    const float* __restrict__ idx_f,  // indices-as-float region of d_out
    float* __restrict__ partials,
    int level)
{
  const int tid = threadIdx.x;
  const size_t row = (size_t)blockIdx.x * 4 + (tid >> 6);
  const int seg = (tid & 63) << 2;
  const int idx = (int)idx_f[row * NQ + level];
  const float4 e = *reinterpret_cast<const float4*>(cb + (size_t)idx * DD + seg);
  float4* rp = reinterpret_cast<float4*>(res + row * DD + seg);
  float4 r = *rp;
  float4 rn = make_float4(r.x - e.x, r.y - e.y, r.z - e.z, r.w - e.w);
  *rp = rn;
  float p = rn.x * rn.x + rn.y * rn.y + rn.z * rn.z + rn.w * rn.w;
  #pragma unroll
  for (int mm = 1; mm < 64; mm <<= 1) p += __shfl_xor(p, mm);
  __shared__ float w4[4];
  if ((tid & 63) == 0) w4[tid >> 6] = p;
  __syncthreads();
  if (tid == 0) partials[blockIdx.x] = w4[0] + w4[1] + w4[2] + w4[3];
}

// ---------------------------------------------------------------------------
// losses[b, level] = sum(partials over batch) / (NN*DD)   (deterministic)
// ---------------------------------------------------------------------------
__global__ __launch_bounds__(256) void rvq_loss(
    const float* __restrict__ partials, float* __restrict__ loss_out, int level)
{
  const int b = blockIdx.x;
  const int tid = threadIdx.x;
  float s = 0.f;
  for (int i = tid; i < 1024; i += 256) s += partials[b * 1024 + i];
  #pragma unroll
  for (int mm = 1; mm < 64; mm <<= 1) s += __shfl_xor(s, mm);
  __shared__ float w4[4];
  if ((tid & 63) == 0) w4[tid >> 6] = s;
  __syncthreads();
  if (tid == 0)
    loss_out[b * NQ + level] = (w4[0] + w4[1] + w4[2] + w4[3]) * (1.0f / 1048576.0f);
}

// ---------------------------------------------------------------------------
// quantized_out = x - res_final
// ---------------------------------------------------------------------------
__global__ __launch_bounds__(256) void rvq_final(
    const float* __restrict__ x, const float* __restrict__ res,
    float* __restrict__ out)
{
  const size_t i = ((size_t)blockIdx.x * 256 + threadIdx.x) * 4;
  float4 a = *reinterpret_cast<const float4*>(x + i);
  float4 b = *reinterpret_cast<const float4*>(res + i);
  *reinterpret_cast<float4*>(out + i) =
      make_float4(a.x - b.x, a.y - b.y, a.z - b.z, a.w - b.w);
}

// ---------------------------------------------------------------------------
// codebook transpose: cbT[q][k][c] <- cb[q][c][k]   (64x64 tiles)
// ---------------------------------------------------------------------------
__global__ __launch_bounds__(256) void rvq_transpose(
    const float* __restrict__ cb, float* __restrict__ cbT)
{
  __shared__ float t[64][65];
  const int tid = threadIdx.x;
  const int bq = blockIdx.x >> 6;      // 64 tiles per level
  const int t2 = blockIdx.x & 63;
  const int ct = t2 >> 2;              // c-tile 0..15
  const int kt = t2 & 3;               // k-tile 0..3
  #pragma unroll
  for (int it = 0; it < 4; ++it) {
    int lin = (it << 8) + tid;         // float4 idx 0..1023
    int r  = lin >> 4;                 // c_local
    int c4 = (lin & 15) << 2;          // k_local
    float4 v = *reinterpret_cast<const float4*>(
        cb + ((size_t)bq * CC + ct * 64 + r) * DD + kt * 64 + c4);
    t[c4 + 0][r] = v.x; t[c4 + 1][r] = v.y; t[c4 + 2][r] = v.z; t[c4 + 3][r] = v.w;
  }
  __syncthreads();
  #pragma unroll
  for (int it = 0; it < 4; ++it) {
    int lin = (it << 8) + tid;
    int r  = lin >> 4;                 // k_local
    int c4 = (lin & 15) << 2;          // c_local
    float4 v = make_float4(t[r][c4], t[r][c4 + 1], t[r][c4 + 2], t[r][c4 + 3]);
    *reinterpret_cast<float4*>(
        cbT + ((size_t)bq * DD + kt * 64 + r) * CC + ct * 64 + c4) = v;
  }
}

// ---------------------------------------------------------------------------
// ||e_c||^2 per code, one wave per code
// ---------------------------------------------------------------------------
__global__ __launch_bounds__(256) void rvq_norms(
    const float* __restrict__ cb, float* __restrict__ cn2)
{
  const int tid = threadIdx.x;
  const size_t code = (size_t)blockIdx.x * 4 + (tid >> 6);
  const int l = tid & 63;
  const float4 v = *reinterpret_cast<const float4*>(cb + code * DD + l * 4);
  float s = v.x * v.x + v.y * v.y + v.z * v.z + v.w * v.w;
  #pragma unroll
  for (int mm = 1; mm < 64; mm <<= 1) s += __shfl_xor(s, mm);
  if (l == 0) cn2[code] = s;
}

extern "C" void kernel_launch(void* const* d_in, const int* in_sizes, int n_in,
                              void* d_out, int out_size, void* d_ws, size_t ws_size,
                              hipStream_t stream) {
  const float* x  = (const float*)d_in[0];  // [8,4096,256]
  const float* cb = (const float*)d_in[1];  // [8,1024,256]
  float* out = (float*)d_out;

  // d_out layout (floats): quantized [ROWS*DD] | indices-as-f32 [ROWS*NQ] | losses [NB*NQ]
  float* out_idx  = out + (size_t)ROWS * DD;
  float* out_loss = out_idx + (size_t)ROWS * NQ;

  // workspace layout (floats)
  float* res      = (float*)d_ws;                       // 8,388,608
  float* cbT      = res + (size_t)ROWS * DD;            // 2,097,152
  float* cn2      = cbT + (size_t)NQ * CC * DD;         // 8,192
  float* partials = cn2 + (size_t)NQ * CC;              // 8,192

  hipMemcpyAsync(res, x, (size_t)ROWS * DD * sizeof(float),
                 hipMemcpyDeviceToDevice, stream);
  rvq_transpose<<<512, 256, 0, stream>>>(cb, cbT);
  rvq_norms<<<2048, 256, 0, stream>>>(cb, cn2);

  for (int q = 0; q < NQ; ++q) {
    rvq_argmin<<<ROWS / MT, 256, 0, stream>>>(
        res, cbT + (size_t)q * DD * CC, cn2 + (size_t)q * CC, out_idx, q);
    rvq_update<<<ROWS / 4, 256, 0, stream>>>(
        res, cb + (size_t)q * CC * DD, out_idx, partials, q);
    rvq_loss<<<NB, 256, 0, stream>>>(partials, out_loss, q);
  }
  rvq_final<<<(size_t)ROWS * DD / 1024, 256, 0, stream>>>(x, res, out);
}

// Round 2
// 2641.577 us; speedup vs baseline: 1.1938x; 1.1938x over previous
//
#include <hip/hip_runtime.h>
#include <math.h>

#define NB 8
#define NN 4096
#define DD 256
#define CC 1024
#define NQ 8
#define ROWS (NB*NN)        // 32768
#define TAU 0.25f           // flag margin; MFMA-path worst-case score err ~0.03

typedef unsigned short u16;
typedef __attribute__((ext_vector_type(8))) short bf16x8;   // 8 bf16 (4 VGPRs)
typedef __attribute__((ext_vector_type(4))) float f32x4;

// ---- exact RNE fp32->bf16 split helpers ----
__device__ __forceinline__ u16 f2bf(float f) {
  unsigned u = __builtin_bit_cast(unsigned, f);
  return (u16)((u + 0x7fffu + ((u >> 16) & 1u)) >> 16);
}
__device__ __forceinline__ float bf2f(u16 h) {
  unsigned u = ((unsigned)h) << 16;
  return __builtin_bit_cast(float, u);
}

// merge sorted pair (w1,d1)<=(w2,d2) into running sorted top-2 (v1,c1,v2,c2)
// all comparisons tie-break toward lower column (numpy first-argmin)
__device__ __forceinline__ void merge_top2(float& v1, float& c1, float& v2, float& c2,
                                           float w1, float d1, float w2, float d2) {
  if (w1 < v1 || (w1 == v1 && d1 < c1)) {
    float nv2, nc2;
    if (v1 < w2 || (v1 == w2 && c1 < d2)) { nv2 = v1; nc2 = c1; }
    else                                  { nv2 = w2; nc2 = d2; }
    v1 = w1; c1 = d1; v2 = nv2; c2 = nc2;
  } else {
    if (w1 < v2 || (w1 == v2 && d1 < c2)) { v2 = w1; c2 = d1; }
  }
}

// ---------------------------------------------------------------------------
// codebook split: cb fp32 -> e_hi, e_lo bf16 (2M elements). Also zeroes cnt.
// ---------------------------------------------------------------------------
__global__ __launch_bounds__(256) void rvq_esplit(
    const float* __restrict__ cb, u16* __restrict__ e_hi, u16* __restrict__ e_lo,
    int* __restrict__ cnt)
{
  if (blockIdx.x == 0 && threadIdx.x < NQ) cnt[threadIdx.x] = 0;
  size_t t = (size_t)blockIdx.x * 256 + threadIdx.x;   // 262144 threads, 8 elem each
  const float4* p = (const float4*)(cb + t * 8);
  float4 f0 = p[0], f1 = p[1];
  u16 h[8], l[8];
  float f[8] = {f0.x, f0.y, f0.z, f0.w, f1.x, f1.y, f1.z, f1.w};
  #pragma unroll
  for (int i = 0; i < 8; ++i) { h[i] = f2bf(f[i]); l[i] = f2bf(f[i] - bf2f(h[i])); }
  uint4 hw = make_uint4((unsigned)h[0] | ((unsigned)h[1] << 16),
                        (unsigned)h[2] | ((unsigned)h[3] << 16),
                        (unsigned)h[4] | ((unsigned)h[5] << 16),
                        (unsigned)h[6] | ((unsigned)h[7] << 16));
  uint4 lw = make_uint4((unsigned)l[0] | ((unsigned)l[1] << 16),
                        (unsigned)l[2] | ((unsigned)l[3] << 16),
                        (unsigned)l[4] | ((unsigned)l[5] << 16),
                        (unsigned)l[6] | ((unsigned)l[7] << 16));
  ((uint4*)e_hi)[t] = hw;
  ((uint4*)e_lo)[t] = lw;
}

// ---------------------------------------------------------------------------
// ||e_c||^2 per code (fp32), one wave per code
// ---------------------------------------------------------------------------
__global__ __launch_bounds__(256) void rvq_norms(
    const float* __restrict__ cb, float* __restrict__ cn2)
{
  const int tid = threadIdx.x;
  const size_t code = (size_t)blockIdx.x * 4 + (tid >> 6);
  const int l = tid & 63;
  const float4 v = *reinterpret_cast<const float4*>(cb + code * DD + l * 4);
  float s = v.x * v.x + v.y * v.y + v.z * v.z + v.w * v.w;
  #pragma unroll
  for (int mm = 1; mm < 64; mm <<= 1) s += __shfl_xor(s, mm);
  if (l == 0) cn2[code] = s;
}

// ---------------------------------------------------------------------------
// MFMA distance + top2 argmin.  Block: 64 rows x all 1024 codes.
// dot = a_hi*e_hi + a_lo*e_hi + a_hi*e_lo  (K=768 as 12 steps of 64)
// score = cn2[c] - 2*dot.  Flags rows with top2 gap <= TAU for exact cleanup.
// ---------------------------------------------------------------------------
__global__ __launch_bounds__(256, 2) void rvq_gemm_top2(
    const float* __restrict__ src,      // residual (fp32), [ROWS][256]
    const u16* __restrict__ e_hi,       // level base, [CC][256]
    const u16* __restrict__ e_lo,
    const float* __restrict__ cn2g,     // level base, [CC]
    float* __restrict__ idx_out,        // indices-as-float region of d_out
    int* __restrict__ list,             // level's flag list [ROWS]
    int* __restrict__ cnt,              // [NQ]
    int level)
{
  __shared__ u16 Ash[64 * 512];   // 64 rows x (hi 256 | lo 256), XOR-swizzled, 64 KB
  __shared__ u16 Bsh[128 * 64];   // 128 codes x 64 k, XOR-swizzled, 16 KB

  const int tid = threadIdx.x;
  const int lane = tid & 63;
  const int wv = tid >> 6;
  const int wr = wv >> 1;         // wave row-half (32 rows)
  const int wc = wv & 1;          // wave col-half (64 of 128 cols)
  const int fr = lane & 15;
  const int fg = lane >> 4;
  const size_t row0 = (size_t)blockIdx.x * 64;

  // ---- stage A panel once: fp32 -> (hi|lo) bf16, swizzled ds_write ----
  {
    const float* arow = src + row0 * DD;
    #pragma unroll
    for (int it = 0; it < 8; ++it) {
      int lin = it * 256 + tid;          // 0..2047 ; 64 rows x 32 groups of 8
      int row = lin >> 5;
      int f8 = lin & 31;
      const float4* p = (const float4*)(arow + (size_t)row * DD + f8 * 8);
      float4 f0 = p[0], f1 = p[1];
      float f[8] = {f0.x, f0.y, f0.z, f0.w, f1.x, f1.y, f1.z, f1.w};
      u16 h[8], l[8];
      #pragma unroll
      for (int i = 0; i < 8; ++i) { h[i] = f2bf(f[i]); l[i] = f2bf(f[i] - bf2f(h[i])); }
      uint4 hw = make_uint4((unsigned)h[0] | ((unsigned)h[1] << 16),
                            (unsigned)h[2] | ((unsigned)h[3] << 16),
                            (unsigned)h[4] | ((unsigned)h[5] << 16),
                            (unsigned)h[6] | ((unsigned)h[7] << 16));
      uint4 lw = make_uint4((unsigned)l[0] | ((unsigned)l[1] << 16),
                            (unsigned)l[2] | ((unsigned)l[3] << 16),
                            (unsigned)l[4] | ((unsigned)l[5] << 16),
                            (unsigned)l[6] | ((unsigned)l[7] << 16));
      int swz = (row & 7) << 4;
      *(uint4*)((char*)Ash + (row << 10) + ((f8 << 4) ^ swz)) = hw;
      *(uint4*)((char*)Ash + (row << 10) + 512 + ((f8 << 4) ^ swz)) = lw;
    }
  }
  __syncthreads();

  // running top-2 per (m,reg) row owned by this lane: 8 rows
  float tv1[8], tv2[8], tc1[8], tc2[8];
  #pragma unroll
  for (int i = 0; i < 8; ++i) { tv1[i] = tv2[i] = __builtin_inff(); tc1[i] = tc2[i] = 1.0e9f; }

  // B prefetch registers (one 128x64 tile = 4 x uint4 per thread)
  uint4 breg[4];
  auto issueB = [&](int s) {          // s = ct*12 + kb, 0..95
    int ct = s / 12, kb = s % 12;
    const u16* bs = ((kb >> 2) == 2) ? e_lo : e_hi;
    const char* base = (const char*)bs + ((size_t)(ct * 128) << 9) + ((kb & 3) << 7);
    #pragma unroll
    for (int it = 0; it < 4; ++it) {
      int lin = it * 256 + tid;        // row = lin>>3 (code in tile), f8 = lin&7
      breg[it] = *(const uint4*)(base + ((size_t)(lin >> 3) << 9) + ((lin & 7) << 4));
    }
  };

  issueB(0);

  for (int ct = 0; ct < 8; ++ct) {
    f32x4 acc[2][4];
    #pragma unroll
    for (int m = 0; m < 2; ++m)
      #pragma unroll
      for (int n = 0; n < 4; ++n) acc[m][n] = (f32x4){0.f, 0.f, 0.f, 0.f};

    for (int kb = 0; kb < 12; ++kb) {
      const int s = ct * 12 + kb;
      __syncthreads();                 // prior Bsh reads complete
      #pragma unroll
      for (int it = 0; it < 4; ++it) { // swizzled ds_write of prefetched tile
        int lin = it * 256 + tid;
        int row = lin >> 3, f8 = lin & 7;
        *(uint4*)((char*)Bsh + (row << 7) + (((f8 << 4)) ^ ((row & 7) << 4))) = breg[it];
      }
      if (s + 1 < 96) issueB(s + 1);   // prefetch next tile; latency hides under MFMA
      __syncthreads();                 // Bsh visible

      const int acol = (((kb >> 2) == 1) ? 512 : 0) + ((kb & 3) << 7);
      bf16x8 af[2][2], bfv[4][2];
      #pragma unroll
      for (int kk = 0; kk < 2; ++kk) {
        #pragma unroll
        for (int m = 0; m < 2; ++m) {
          int row = wr * 32 + m * 16 + fr;
          int col = acol + kk * 64 + (fg << 4);
          af[m][kk] = *(const bf16x8*)((const char*)Ash + (row << 10) + (col ^ ((row & 7) << 4)));
        }
        #pragma unroll
        for (int n = 0; n < 4; ++n) {
          int row = wc * 64 + n * 16 + fr;
          int col = kk * 64 + (fg << 4);
          bfv[n][kk] = *(const bf16x8*)((const char*)Bsh + (row << 7) + (col ^ ((row & 7) << 4)));
        }
      }
      #pragma unroll
      for (int kk = 0; kk < 2; ++kk)
        #pragma unroll
        for (int m = 0; m < 2; ++m)
          #pragma unroll
          for (int n = 0; n < 4; ++n)
            acc[m][n] = __builtin_amdgcn_mfma_f32_16x16x32_bf16(
                af[m][kk], bfv[n][kk], acc[m][n], 0, 0, 0);
    }

    // ---- fold this 128-col tile into running top2 ----
    float cnv[4];
    #pragma unroll
    for (int n = 0; n < 4; ++n) cnv[n] = cn2g[ct * 128 + wc * 64 + n * 16 + fr];
    #pragma unroll
    for (int m = 0; m < 2; ++m)
      #pragma unroll
      for (int r = 0; r < 4; ++r) {
        const int i8 = m * 4 + r;
        #pragma unroll
        for (int n = 0; n < 4; ++n) {
          float sv = fmaf(-2.f, acc[m][n][r], cnv[n]);
          float cf = (float)(ct * 128 + wc * 64 + n * 16 + fr);
          if (sv < tv1[i8] || (sv == tv1[i8] && cf < tc1[i8])) {
            tv2[i8] = tv1[i8]; tc2[i8] = tc1[i8]; tv1[i8] = sv; tc1[i8] = cf;
          } else if (sv < tv2[i8] || (sv == tv2[i8] && cf < tc2[i8])) {
            tv2[i8] = sv; tc2[i8] = cf;
          }
        }
      }
  }

  // ---- reduce across 16 lanes of each row group, then across wc halves ----
  __syncthreads();                       // Bsh now reusable as scratch
  float4* shtop = (float4*)Bsh;          // [wc][64 rows]
  #pragma unroll
  for (int m = 0; m < 2; ++m)
    #pragma unroll
    for (int r = 0; r < 4; ++r) {
      const int i8 = m * 4 + r;
      float v1 = tv1[i8], v2 = tv2[i8], c1 = tc1[i8], c2 = tc2[i8];
      #pragma unroll
      for (int mk = 1; mk < 16; mk <<= 1) {
        float w1 = __shfl_xor(v1, mk), d1 = __shfl_xor(c1, mk);
        float w2 = __shfl_xor(v2, mk), d2 = __shfl_xor(c2, mk);
        merge_top2(v1, c1, v2, c2, w1, d1, w2, d2);
      }
      if (fr == 0)
        shtop[wc * 64 + wr * 32 + m * 16 + fg * 4 + r] = make_float4(v1, c1, v2, c2);
    }
  __syncthreads();

  if (tid < 64) {
    float4 A4 = shtop[tid], B4 = shtop[64 + tid];
    float v1 = A4.x, c1 = A4.y, v2 = A4.z, c2 = A4.w;
    merge_top2(v1, c1, v2, c2, B4.x, B4.y, B4.z, B4.w);
    const size_t grow = row0 + tid;
    idx_out[grow * NQ + level] = c1;
    if (v2 - v1 <= TAU) {
      int p = atomicAdd(cnt + level, 1);
      list[p] = (int)grow;
    }
  }
}

// ---------------------------------------------------------------------------
// exact fp32 re-argmin for flagged rows (full 1024-code scan, round-1 math)
// ---------------------------------------------------------------------------
__global__ __launch_bounds__(256) void rvq_cleanup(
    const float* __restrict__ src, const float* __restrict__ cbq,
    const float* __restrict__ cn2q, const int* __restrict__ list,
    const int* __restrict__ cnt, float* __restrict__ idx_out, int level)
{
  __shared__ __align__(16) float rsh[DD];
  __shared__ float wmin[4];
  __shared__ int wcol[4];
  const int tid = threadIdx.x;
  const int n = cnt[level];
  for (int it = blockIdx.x; it < n; it += gridDim.x) {
    const int row = list[it];
    __syncthreads();                     // protect rsh/wmin reuse
    rsh[tid] = src[(size_t)row * DD + tid];
    __syncthreads();
    float bv = __builtin_inff(); int bc = 1 << 29;
    #pragma unroll
    for (int cc4 = 0; cc4 < 4; ++cc4) {
      const int c = cc4 * 256 + tid;     // within-thread c ascending
      const float4* ep = (const float4*)(cbq + (size_t)c * DD);
      float dot = 0.f;
      #pragma unroll 8
      for (int k4 = 0; k4 < 64; ++k4) {
        float4 e4 = ep[k4];
        float4 r4 = *(const float4*)&rsh[k4 * 4];
        dot = fmaf(r4.x, e4.x, dot);
        dot = fmaf(r4.y, e4.y, dot);
        dot = fmaf(r4.z, e4.z, dot);
        dot = fmaf(r4.w, e4.w, dot);
      }
      float s = fmaf(-2.f, dot, cn2q[c]);
      if (s < bv || (s == bv && c < bc)) { bv = s; bc = c; }
    }
    #pragma unroll
    for (int mk = 1; mk < 64; mk <<= 1) {
      float ov = __shfl_xor(bv, mk); int oc = __shfl_xor(bc, mk);
      if (ov < bv || (ov == bv && oc < bc)) { bv = ov; bc = oc; }
    }
    if ((tid & 63) == 0) { wmin[tid >> 6] = bv; wcol[tid >> 6] = bc; }
    __syncthreads();
    if (tid == 0) {
      float v = wmin[0]; int c = wcol[0];
      #pragma unroll
      for (int w = 1; w < 4; ++w)
        if (wmin[w] < v || (wmin[w] == v && wcol[w] < c)) { v = wmin[w]; c = wcol[w]; }
      idx_out[(size_t)row * NQ + level] = (float)c;
    }
  }
}

// ---------------------------------------------------------------------------
// residual update: res = src - e[idx]; per-block partial loss sums (4 rows)
// ---------------------------------------------------------------------------
__global__ __launch_bounds__(256) void rvq_update(
    const float* __restrict__ src, float* __restrict__ res,
    const float* __restrict__ cbq, const float* __restrict__ idx_f,
    float* __restrict__ partials, int level)
{
  const int tid = threadIdx.x;
  const size_t row = (size_t)blockIdx.x * 4 + (tid >> 6);
  const int seg = (tid & 63) << 2;
  const int idx = (int)idx_f[row * NQ + level];
  const float4 e = *reinterpret_cast<const float4*>(cbq + (size_t)idx * DD + seg);
  const float4 r = *reinterpret_cast<const float4*>(src + row * DD + seg);
  float4 rn = make_float4(r.x - e.x, r.y - e.y, r.z - e.z, r.w - e.w);
  *reinterpret_cast<float4*>(res + row * DD + seg) = rn;
  float p = rn.x * rn.x + rn.y * rn.y + rn.z * rn.z + rn.w * rn.w;
  #pragma unroll
  for (int mm = 1; mm < 64; mm <<= 1) p += __shfl_xor(p, mm);
  __shared__ float w4[4];
  if ((tid & 63) == 0) w4[tid >> 6] = p;
  __syncthreads();
  if (tid == 0) partials[blockIdx.x] = w4[0] + w4[1] + w4[2] + w4[3];
}

__global__ __launch_bounds__(256) void rvq_loss(
    const float* __restrict__ partials, float* __restrict__ loss_out, int level)
{
  const int b = blockIdx.x;
  const int tid = threadIdx.x;
  float s = 0.f;
  for (int i = tid; i < 1024; i += 256) s += partials[b * 1024 + i];
  #pragma unroll
  for (int mm = 1; mm < 64; mm <<= 1) s += __shfl_xor(s, mm);
  __shared__ float w4[4];
  if ((tid & 63) == 0) w4[tid >> 6] = s;
  __syncthreads();
  if (tid == 0)
    loss_out[b * NQ + level] = (w4[0] + w4[1] + w4[2] + w4[3]) * (1.0f / 1048576.0f);
}

// quantized_out = x - res, in place (res lives in the quantized region of d_out)
__global__ __launch_bounds__(256) void rvq_final(
    const float* __restrict__ x, float* out)
{
  const size_t i = ((size_t)blockIdx.x * 256 + threadIdx.x) * 4;
  float4 a = *reinterpret_cast<const float4*>(x + i);
  float4 b = *reinterpret_cast<const float4*>(out + i);
  *reinterpret_cast<float4*>(out + i) =
      make_float4(a.x - b.x, a.y - b.y, a.z - b.z, a.w - b.w);
}

extern "C" void kernel_launch(void* const* d_in, const int* in_sizes, int n_in,
                              void* d_out, int out_size, void* d_ws, size_t ws_size,
                              hipStream_t stream) {
  const float* x  = (const float*)d_in[0];  // [8,4096,256]
  const float* cb = (const float*)d_in[1];  // [8,1024,256]
  float* out = (float*)d_out;

  // d_out layout (floats): quantized [ROWS*DD] | indices-as-f32 [ROWS*NQ] | losses [NB*NQ]
  float* res      = out;                         // residual shares quantized region
  float* out_idx  = out + (size_t)ROWS * DD;
  float* out_loss = out_idx + (size_t)ROWS * NQ;

  // workspace (~9.6 MB)
  char* w = (char*)d_ws;
  u16* e_hi = (u16*)w;                                   w += (size_t)NQ * CC * DD * 2;
  u16* e_lo = (u16*)w;                                   w += (size_t)NQ * CC * DD * 2;
  float* cn2 = (float*)w;                                w += (size_t)NQ * CC * 4;
  int* list = (int*)w;                                   w += (size_t)NQ * ROWS * 4;
  int* cnt = (int*)w;                                    w += 64;
  float* partials = (float*)w;                           w += (size_t)(ROWS / 4) * 4;

  rvq_esplit<<<1024, 256, 0, stream>>>(cb, e_hi, e_lo, cnt);
  rvq_norms<<<2048, 256, 0, stream>>>(cb, cn2);

  for (int q = 0; q < NQ; ++q) {
    const float* src = q ? res : x;
    const size_t eo = (size_t)q * CC * DD;
    rvq_gemm_top2<<<ROWS / 64, 256, 0, stream>>>(
        src, e_hi + eo, e_lo + eo, cn2 + (size_t)q * CC,
        out_idx, list + (size_t)q * ROWS, cnt, q);
    rvq_cleanup<<<256, 256, 0, stream>>>(
        src, cb + eo, cn2 + (size_t)q * CC, list + (size_t)q * ROWS, cnt, out_idx, q);
    rvq_update<<<ROWS / 4, 256, 0, stream>>>(
        src, res, cb + eo, out_idx, partials, q);
    rvq_loss<<<NB, 256, 0, stream>>>(partials, out_loss, q);
  }
  rvq_final<<<ROWS * DD / 1024, 256, 0, stream>>>(x, out);
}

// Round 3
// 1902.218 us; speedup vs baseline: 1.6578x; 1.3887x over previous
//
#include <hip/hip_runtime.h>
#include <math.h>

#define NB 8
#define NN 4096
#define DD 256
#define CC 1024
#define NQ 8
#define ROWS (NB*NN)        // 32768
#define TAU 0.25f           // flag margin; bf16-split score err << this

typedef unsigned short u16;
typedef __attribute__((ext_vector_type(8))) short bf16x8;   // 8 bf16 (4 VGPRs)
typedef __attribute__((ext_vector_type(4))) float f32x4;

// ---- exact RNE fp32->bf16 split helpers ----
__device__ __forceinline__ u16 f2bf(float f) {
  unsigned u = __builtin_bit_cast(unsigned, f);
  return (u16)((u + 0x7fffu + ((u >> 16) & 1u)) >> 16);
}
__device__ __forceinline__ float bf2f(u16 h) {
  unsigned u = ((unsigned)h) << 16;
  return __builtin_bit_cast(float, u);
}
__device__ __forceinline__ void split4(float4 f, ushort4& h, ushort4& l) {
  h.x = f2bf(f.x); h.y = f2bf(f.y); h.z = f2bf(f.z); h.w = f2bf(f.w);
  l.x = f2bf(f.x - bf2f(h.x)); l.y = f2bf(f.y - bf2f(h.y));
  l.z = f2bf(f.z - bf2f(h.z)); l.w = f2bf(f.w - bf2f(h.w));
}

// merge candidate pair (w1,d1)<=(w2,d2) into running sorted top-2
__device__ __forceinline__ void merge_top2(float& v1, float& c1, float& v2, float& c2,
                                           float w1, float d1, float w2, float d2) {
  if (w1 < v1 || (w1 == v1 && d1 < c1)) {
    float nv2, nc2;
    if (v1 < w2 || (v1 == w2 && c1 < d2)) { nv2 = v1; nc2 = c1; }
    else                                  { nv2 = w2; nc2 = d2; }
    v1 = w1; c1 = d1; v2 = nv2; c2 = nc2;
  } else {
    if (w1 < v2 || (w1 == v2 && d1 < c2)) { v2 = w1; c2 = d1; }
  }
}

__device__ __forceinline__ void gload16(const void* g, void* l) {
  __builtin_amdgcn_global_load_lds(
      (const __attribute__((address_space(1))) unsigned int*)g,
      (__attribute__((address_space(3))) unsigned int*)l, 16, 0, 0);
}

// ---------------------------------------------------------------------------
// x -> rsplit [ROWS][hi 256 | lo 256] bf16 ; also zero cnt
// ---------------------------------------------------------------------------
__global__ __launch_bounds__(256) void rvq_split0(
    const float* __restrict__ x, u16* __restrict__ rsplit, int* __restrict__ cnt)
{
  if (blockIdx.x == 0 && threadIdx.x < NQ) cnt[threadIdx.x] = 0;
  const size_t f = (size_t)blockIdx.x * 256 + threadIdx.x;   // float4 id (2M)
  const size_t row = f >> 6;
  const int c4 = (int)(f & 63) << 2;
  float4 v = ((const float4*)x)[f];
  ushort4 h, l; split4(v, h, l);
  *(ushort4*)(rsplit + row * 512 + c4) = h;
  *(ushort4*)(rsplit + row * 512 + 256 + c4) = l;
}

// ---------------------------------------------------------------------------
// per-level codebook split: cb[q] fp32 -> esplit [CC][hi|lo] bf16
// ---------------------------------------------------------------------------
__global__ __launch_bounds__(256) void rvq_esplit(
    const float* __restrict__ cbq, u16* __restrict__ esp)
{
  const int f = blockIdx.x * 256 + threadIdx.x;              // float4 id (64K)
  const int row = f >> 6;
  const int c4 = (f & 63) << 2;
  float4 v = ((const float4*)cbq)[f];
  ushort4 h, l; split4(v, h, l);
  *(ushort4*)(esp + (size_t)row * 512 + c4) = h;
  *(ushort4*)(esp + (size_t)row * 512 + 256 + c4) = l;
}

// ---------------------------------------------------------------------------
// ||e_c||^2 for all levels (fp32), one wave per code
// ---------------------------------------------------------------------------
__global__ __launch_bounds__(256) void rvq_norms(
    const float* __restrict__ cb, float* __restrict__ cn2)
{
  const int tid = threadIdx.x;
  const size_t code = (size_t)blockIdx.x * 4 + (tid >> 6);
  const int l = tid & 63;
  const float4 v = *reinterpret_cast<const float4*>(cb + code * DD + l * 4);
  float s = v.x * v.x + v.y * v.y + v.z * v.z + v.w * v.w;
  #pragma unroll
  for (int mm = 1; mm < 64; mm <<= 1) s += __shfl_xor(s, mm);
  if (l == 0) cn2[code] = s;
}

// ---------------------------------------------------------------------------
// m97-style MFMA GEMM + fused per-block top2.
// Grid: 256 mb x 8 nb. Block: 128 rows x 128 codes, K=768 virtual
// (t<8: hiA*hiB, t<16: hiA*loB, t<24: loA*hiB), BK=32, 24 steps.
// Double-buffered LDS via global_load_lds(16B), ONE barrier per step.
// ---------------------------------------------------------------------------
__global__ __launch_bounds__(256) void rvq_gemm97(
    const u16* __restrict__ rsplit,   // [ROWS][512]
    const u16* __restrict__ esp,      // [CC][512]  (level)
    const float* __restrict__ cn2q,   // [CC]       (level)
    float4* __restrict__ top2)        // [ROWS][8]
{
  __shared__ u16 As[2][128 * 32];     // 8 KB each
  __shared__ u16 Bs[2][128 * 32];

  const int tid = threadIdx.x;
  const int lane = tid & 63;
  const int wv = tid >> 6;
  const int wr = wv >> 1, wc = wv & 1;
  const int fr = lane & 15, fg = lane >> 4;
  const int mb = blockIdx.x >> 3, nb = blockIdx.x & 7;
  const size_t row0 = (size_t)mb * 128;
  const int lrow = lane >> 2;         // row within 16-row wave chunk
  const int lc4 = lane & 3;           // 16B slot within 64B row

  auto stage = [&](int t, int cur) {
    const int ao = (t < 16) ? ((t & 7) << 5) : (256 + ((t - 16) << 5));
    const int bo = (t < 8) ? (t << 5) : (t < 16 ? 256 + ((t - 8) << 5) : ((t - 16) << 5));
    #pragma unroll
    for (int r = 0; r < 2; ++r) {
      const int r0 = ((r << 2) + wv) << 4;                    // chunk first row
      const int grow = r0 + lrow;
      gload16(rsplit + (row0 + grow) * 512 + ao + (lc4 << 3), &As[cur][r0 * 32]);
      gload16(esp + (size_t)(nb * 128 + grow) * 512 + bo + (lc4 << 3), &Bs[cur][r0 * 32]);
    }
  };

  f32x4 acc[4][4];
  #pragma unroll
  for (int m = 0; m < 4; ++m)
    #pragma unroll
    for (int n = 0; n < 4; ++n) acc[m][n] = (f32x4){0.f, 0.f, 0.f, 0.f};

  stage(0, 0);
  __syncthreads();

  for (int t = 0; t < 24; ++t) {
    const int cur = t & 1;
    if (t + 1 < 24) stage(t + 1, cur ^ 1);   // issue-early: latency hides under MFMA
    bf16x8 a[4], b[4];
    #pragma unroll
    for (int m = 0; m < 4; ++m)
      a[m] = *(const bf16x8*)&As[cur][(wr * 64 + m * 16 + fr) * 32 + fg * 8];
    #pragma unroll
    for (int n = 0; n < 4; ++n)
      b[n] = *(const bf16x8*)&Bs[cur][(wc * 64 + n * 16 + fr) * 32 + fg * 8];
    #pragma unroll
    for (int m = 0; m < 4; ++m)
      #pragma unroll
      for (int n = 0; n < 4; ++n)
        acc[m][n] = __builtin_amdgcn_mfma_f32_16x16x32_bf16(a[m], b[n], acc[m][n], 0, 0, 0);
    __syncthreads();                          // drains vmcnt -> next buf ready
  }

  // ---- epilogue: per-row top2 over this block's 128 cols ----
  float4* shtop = (float4*)&As[0][0];         // 256 float4 (reuse LDS)
  float cnv[4];
  #pragma unroll
  for (int n = 0; n < 4; ++n) cnv[n] = cn2q[nb * 128 + wc * 64 + n * 16 + fr];
  #pragma unroll
  for (int m = 0; m < 4; ++m)
    #pragma unroll
    for (int r = 0; r < 4; ++r) {
      float v1 = __builtin_inff(), c1 = 1.0e9f, v2 = __builtin_inff(), c2 = 1.0e9f;
      #pragma unroll
      for (int n = 0; n < 4; ++n) {
        const float sv = fmaf(-2.f, acc[m][n][r], cnv[n]);
        const float cf = (float)(nb * 128 + wc * 64 + n * 16 + fr);
        if (sv < v1 || (sv == v1 && cf < c1)) { v2 = v1; c2 = c1; v1 = sv; c1 = cf; }
        else if (sv < v2 || (sv == v2 && cf < c2)) { v2 = sv; c2 = cf; }
      }
      #pragma unroll
      for (int mk = 1; mk < 16; mk <<= 1) {
        float w1 = __shfl_xor(v1, mk), d1 = __shfl_xor(c1, mk);
        float w2 = __shfl_xor(v2, mk), d2 = __shfl_xor(c2, mk);
        merge_top2(v1, c1, v2, c2, w1, d1, w2, d2);
      }
      if (fr == 0)
        shtop[wc * 128 + wr * 64 + m * 16 + fg * 4 + r] = make_float4(v1, c1, v2, c2);
    }
  __syncthreads();

  if (tid < 128) {
    float4 A4 = shtop[tid], B4 = shtop[128 + tid];
    float v1 = A4.x, c1 = A4.y, v2 = A4.z, c2 = A4.w;
    merge_top2(v1, c1, v2, c2, B4.x, B4.y, B4.z, B4.w);
    top2[(row0 + tid) * 8 + nb] = make_float4(v1, c1, v2, c2);
  }
}

// ---------------------------------------------------------------------------
// merge 8 per-block top2 partials per row -> index + flag list
// ---------------------------------------------------------------------------
__global__ __launch_bounds__(256) void rvq_reduce(
    const float4* __restrict__ top2, float* __restrict__ idx_out,
    int* __restrict__ list, int* __restrict__ cnt, int level)
{
  const int row = blockIdx.x * 256 + threadIdx.x;
  const float4* p = top2 + (size_t)row * 8;
  float4 f = p[0];
  float v1 = f.x, c1 = f.y, v2 = f.z, c2 = f.w;
  #pragma unroll
  for (int i = 1; i < 8; ++i) {                 // nb ascending = col ascending
    float4 g = p[i];
    merge_top2(v1, c1, v2, c2, g.x, g.y, g.z, g.w);
  }
  idx_out[(size_t)row * NQ + level] = c1;
  if (v2 - v1 <= TAU) {
    int q = atomicAdd(cnt + level, 1);
    list[q] = row;
  }
}

// ---------------------------------------------------------------------------
// exact fp32 re-argmin for flagged rows (full 1024-code scan)
// ---------------------------------------------------------------------------
__global__ __launch_bounds__(256) void rvq_cleanup(
    const float* __restrict__ src, const float* __restrict__ cbq,
    const float* __restrict__ cn2q, const int* __restrict__ list,
    const int* __restrict__ cnt, float* __restrict__ idx_out, int level)
{
  __shared__ __align__(16) float rsh[DD];
  __shared__ float wmin[4];
  __shared__ int wcol[4];
  const int tid = threadIdx.x;
  const int n = cnt[level];
  for (int it = blockIdx.x; it < n; it += gridDim.x) {
    const int row = list[it];
    __syncthreads();
    rsh[tid] = src[(size_t)row * DD + tid];
    __syncthreads();
    float bv = __builtin_inff(); int bc = 1 << 29;
    #pragma unroll
    for (int cc4 = 0; cc4 < 4; ++cc4) {
      const int c = cc4 * 256 + tid;
      const float4* ep = (const float4*)(cbq + (size_t)c * DD);
      float dot = 0.f;
      #pragma unroll 8
      for (int k4 = 0; k4 < 64; ++k4) {
        float4 e4 = ep[k4];
        float4 r4 = *(const float4*)&rsh[k4 * 4];
        dot = fmaf(r4.x, e4.x, dot);
        dot = fmaf(r4.y, e4.y, dot);
        dot = fmaf(r4.z, e4.z, dot);
        dot = fmaf(r4.w, e4.w, dot);
      }
      float s = fmaf(-2.f, dot, cn2q[c]);
      if (s < bv || (s == bv && c < bc)) { bv = s; bc = c; }
    }
    #pragma unroll
    for (int mk = 1; mk < 64; mk <<= 1) {
      float ov = __shfl_xor(bv, mk); int oc = __shfl_xor(bc, mk);
      if (ov < bv || (ov == bv && oc < bc)) { bv = ov; bc = oc; }
    }
    if ((tid & 63) == 0) { wmin[tid >> 6] = bv; wcol[tid >> 6] = bc; }
    __syncthreads();
    if (tid == 0) {
      float v = wmin[0]; int c = wcol[0];
      #pragma unroll
      for (int w = 1; w < 4; ++w)
        if (wmin[w] < v || (wmin[w] == v && wcol[w] < c)) { v = wmin[w]; c = wcol[w]; }
      idx_out[(size_t)row * NQ + level] = (float)c;
    }
  }
}

// ---------------------------------------------------------------------------
// residual update: res = src - e[idx]; also emit bf16 hi/lo split for next
// level's GEMM; per-block partial loss sums (4 rows/block)
// ---------------------------------------------------------------------------
__global__ __launch_bounds__(256) void rvq_update_split(
    const float* __restrict__ src, float* __restrict__ res,
    const float* __restrict__ cbq, const float* __restrict__ idx_f,
    u16* __restrict__ rsplit, float* __restrict__ partials, int level)
{
  const int tid = threadIdx.x;
  const size_t row = (size_t)blockIdx.x * 4 + (tid >> 6);
  const int seg = (tid & 63) << 2;
  const int idx = (int)idx_f[row * NQ + level];
  const float4 e = *reinterpret_cast<const float4*>(cbq + (size_t)idx * DD + seg);
  const float4 r = *reinterpret_cast<const float4*>(src + row * DD + seg);
  float4 rn = make_float4(r.x - e.x, r.y - e.y, r.z - e.z, r.w - e.w);
  *reinterpret_cast<float4*>(res + row * DD + seg) = rn;
  if (level < 7) {
    ushort4 h, l; split4(rn, h, l);
    *(ushort4*)(rsplit + row * 512 + seg) = h;
    *(ushort4*)(rsplit + row * 512 + 256 + seg) = l;
  }
  float p = rn.x * rn.x + rn.y * rn.y + rn.z * rn.z + rn.w * rn.w;
  #pragma unroll
  for (int mm = 1; mm < 64; mm <<= 1) p += __shfl_xor(p, mm);
  __shared__ float w4[4];
  if ((tid & 63) == 0) w4[tid >> 6] = p;
  __syncthreads();
  if (tid == 0) partials[blockIdx.x] = w4[0] + w4[1] + w4[2] + w4[3];
}

__global__ __launch_bounds__(256) void rvq_loss(
    const float* __restrict__ partials, float* __restrict__ loss_out, int level)
{
  const int b = blockIdx.x;
  const int tid = threadIdx.x;
  float s = 0.f;
  for (int i = tid; i < 1024; i += 256) s += partials[b * 1024 + i];
  #pragma unroll
  for (int mm = 1; mm < 64; mm <<= 1) s += __shfl_xor(s, mm);
  __shared__ float w4[4];
  if ((tid & 63) == 0) w4[tid >> 6] = s;
  __syncthreads();
  if (tid == 0)
    loss_out[b * NQ + level] = (w4[0] + w4[1] + w4[2] + w4[3]) * (1.0f / 1048576.0f);
}

// quantized_out = x - res, in place (res lives in quantized region of d_out)
__global__ __launch_bounds__(256) void rvq_final(
    const float* __restrict__ x, float* out)
{
  const size_t i = ((size_t)blockIdx.x * 256 + threadIdx.x) * 4;
  float4 a = *reinterpret_cast<const float4*>(x + i);
  float4 b = *reinterpret_cast<const float4*>(out + i);
  *reinterpret_cast<float4*>(out + i) =
      make_float4(a.x - b.x, a.y - b.y, a.z - b.z, a.w - b.w);
}

extern "C" void kernel_launch(void* const* d_in, const int* in_sizes, int n_in,
                              void* d_out, int out_size, void* d_ws, size_t ws_size,
                              hipStream_t stream) {
  const float* x  = (const float*)d_in[0];  // [8,4096,256]
  const float* cb = (const float*)d_in[1];  // [8,1024,256]
  float* out = (float*)d_out;

  // d_out layout (floats): quantized [ROWS*DD] | indices [ROWS*NQ] | losses [NB*NQ]
  float* res      = out;                    // residual shares quantized region
  float* out_idx  = out + (size_t)ROWS * DD;
  float* out_loss = out_idx + (size_t)ROWS * NQ;

  // workspace (~39.9 MB)
  char* w = (char*)d_ws;
  u16* rsplit = (u16*)w;                         w += (size_t)ROWS * 512 * 2;   // 32 MB
  float4* top2 = (float4*)w;                     w += (size_t)ROWS * 8 * 16;    // 4 MB
  u16* esp = (u16*)w;                            w += (size_t)CC * 512 * 2;     // 1 MB
  int* list = (int*)w;                           w += (size_t)NQ * ROWS * 4;    // 1 MB
  float* cn2 = (float*)w;                        w += (size_t)NQ * CC * 4;
  float* partials = (float*)w;                   w += (size_t)(ROWS / 4) * 4;
  int* cnt = (int*)w;                            w += 64;

  rvq_split0<<<8192, 256, 0, stream>>>(x, rsplit, cnt);
  rvq_norms<<<2048, 256, 0, stream>>>(cb, cn2);

  for (int q = 0; q < NQ; ++q) {
    const float* srcres = q ? res : x;
    const size_t eo = (size_t)q * CC * DD;
    rvq_esplit<<<256, 256, 0, stream>>>(cb + eo, esp);
    rvq_gemm97<<<2048, 256, 0, stream>>>(rsplit, esp, cn2 + (size_t)q * CC, top2);
    rvq_reduce<<<128, 256, 0, stream>>>(top2, out_idx, list + (size_t)q * ROWS, cnt, q);
    rvq_cleanup<<<512, 256, 0, stream>>>(
        srcres, cb + eo, cn2 + (size_t)q * CC, list + (size_t)q * ROWS, cnt, out_idx, q);
    rvq_update_split<<<ROWS / 4, 256, 0, stream>>>(
        srcres, res, cb + eo, out_idx, rsplit, partials, q);
    rvq_loss<<<NB, 256, 0, stream>>>(partials, out_loss, q);
  }
  rvq_final<<<ROWS * DD / 1024, 256, 0, stream>>>(x, out);
}